// Round 1
// baseline (646.678 us; speedup 1.0000x reference)
//
#include <hip/hip_runtime.h>
#include <hip/hip_bf16.h>

// ---------------- degree / norm ----------------
__global__ void count_kernel(const int* __restrict__ dst, int E, int* __restrict__ cnt) {
    int e = blockIdx.x * blockDim.x + threadIdx.x;
    if (e < E) atomicAdd(&cnt[dst[e]], 1);
}

__global__ void dinv_kernel(const int* __restrict__ cnt, float* __restrict__ dinv, int n) {
    int i = blockIdx.x * blockDim.x + threadIdx.x;
    if (i < n) dinv[i] = rsqrtf((float)cnt[i] + 1.0f);
}

// ---------------- exclusive scan (3 kernels) ----------------
__global__ void scan_block(const int* __restrict__ cnt, int* __restrict__ rowptr,
                           int* __restrict__ bsum, int n) {
    __shared__ int sd[256];
    int i = blockIdx.x * 256 + threadIdx.x;
    int v = (i < n) ? cnt[i] : 0;
    sd[threadIdx.x] = v;
    __syncthreads();
    for (int off = 1; off < 256; off <<= 1) {
        int t = (threadIdx.x >= off) ? sd[threadIdx.x - off] : 0;
        __syncthreads();
        sd[threadIdx.x] += t;
        __syncthreads();
    }
    if (i < n) rowptr[i] = sd[threadIdx.x] - v;     // exclusive within block
    if (threadIdx.x == 255) bsum[blockIdx.x] = sd[255];
}

__global__ void scan_sums(int* __restrict__ bsum, int* __restrict__ rowptr, int nb, int n) {
    __shared__ int sd[512];
    int v = (threadIdx.x < nb) ? bsum[threadIdx.x] : 0;
    sd[threadIdx.x] = v;
    __syncthreads();
    for (int off = 1; off < 512; off <<= 1) {
        int t = (threadIdx.x >= off) ? sd[threadIdx.x - off] : 0;
        __syncthreads();
        sd[threadIdx.x] += t;
        __syncthreads();
    }
    if (threadIdx.x < nb) bsum[threadIdx.x] = sd[threadIdx.x] - v;  // exclusive
    if (threadIdx.x == 511) rowptr[n] = sd[511];                    // total = E
}

__global__ void scan_add(int* __restrict__ rowptr, const int* __restrict__ bsum, int n) {
    int i = blockIdx.x * 256 + threadIdx.x;
    if (i < n) rowptr[i] += bsum[blockIdx.x];
}

// ---------------- CSR fill ----------------
__global__ void fill_kernel(const int* __restrict__ src, const int* __restrict__ dst, int E,
                            const int* __restrict__ rowptr, int* __restrict__ fill,
                            int* __restrict__ srcids) {
    int e = blockIdx.x * blockDim.x + threadIdx.x;
    if (e < E) {
        int d = dst[e];
        int p = atomicAdd(&fill[d], 1);
        srcids[rowptr[d] + p] = src[e];
    }
}

// ---------------- fp32 tiled GEMM (C = A @ B), row-major ----------------
template <int BM, int BN, int BK, int TM, int TN>
__launch_bounds__(256)
__global__ void gemm_nn(const float* __restrict__ A, const float* __restrict__ B,
                        float* __restrict__ C, int M, int N, int K) {
    __shared__ float As[BK][BM + 1];   // transposed store: As[k][m]
    __shared__ float Bs[BK][BN];
    const int tid = threadIdx.x;
    const int tx = tid % (BN / TN);
    const int ty = tid / (BN / TN);
    const int row0 = blockIdx.y * BM;
    const int col0 = blockIdx.x * BN;

    float acc[TM][TN];
#pragma unroll
    for (int i = 0; i < TM; i++)
#pragma unroll
        for (int j = 0; j < TN; j++) acc[i][j] = 0.f;

    for (int k0 = 0; k0 < K; k0 += BK) {
        // A tile: BM x BK, float4 over K, transposed into LDS
        constexpr int ARUN = BM * BK / (256 * 4);
#pragma unroll
        for (int p = 0; p < ARUN; p++) {
            int idx = (tid + p * 256) * 4;
            int r = idx / BK;
            int kk = idx % BK;
            int gr = row0 + r;
            if (gr >= M) gr = M - 1;                 // clamp; stores are guarded
            float4 a = *(const float4*)(A + (size_t)gr * K + k0 + kk);
            As[kk + 0][r] = a.x;
            As[kk + 1][r] = a.y;
            As[kk + 2][r] = a.z;
            As[kk + 3][r] = a.w;
        }
        // B tile: BK x BN
        constexpr int BRUN = BK * BN / (256 * 4);
#pragma unroll
        for (int p = 0; p < BRUN; p++) {
            int idx = (tid + p * 256) * 4;
            int r = idx / BN;
            int cc = idx % BN;
            *(float4*)(&Bs[r][cc]) = *(const float4*)(B + (size_t)(k0 + r) * N + cc);
        }
        __syncthreads();

#pragma unroll 8
        for (int kk = 0; kk < BK; kk++) {
            float av[TM], bv[TN];
#pragma unroll
            for (int i = 0; i < TM; i++) av[i] = As[kk][ty * TM + i];
#pragma unroll
            for (int j = 0; j < TN; j++) bv[j] = Bs[kk][tx * TN + j];
#pragma unroll
            for (int i = 0; i < TM; i++)
#pragma unroll
                for (int j = 0; j < TN; j++) acc[i][j] += av[i] * bv[j];
        }
        __syncthreads();
    }

#pragma unroll
    for (int i = 0; i < TM; i++) {
        int gr = row0 + ty * TM + i;
        if (gr < M) {
#pragma unroll
            for (int j0 = 0; j0 < TN; j0 += 4) {
                float4 w;
                w.x = acc[i][j0 + 0];
                w.y = acc[i][j0 + 1];
                w.z = acc[i][j0 + 2];
                w.w = acc[i][j0 + 3];
                *(float4*)(C + (size_t)gr * N + col0 + tx * TN + j0) = w;
            }
        }
    }
}

// ---------------- aggregation: out[d] = (sum_{s in in(d)} h[s]*dinv[s] + h[d]*dinv[d]) * dinv[d] + b  ----------------
template <int F, bool RELU>
__launch_bounds__(256)
__global__ void agg_kernel(const float* __restrict__ h, const float* __restrict__ bias,
                           const int* __restrict__ rowptr, const int* __restrict__ srcids,
                           const float* __restrict__ dinv, float* __restrict__ out, int n) {
    constexpr int V = F / 64;  // floats per lane
    const int wv = threadIdx.x >> 6;
    const int lane = threadIdx.x & 63;
    const int node = blockIdx.x * (256 >> 6) + wv;
    if (node >= n) return;

    const float dn = dinv[node];
    float acc[V];
    const float* hr = h + (size_t)node * F + lane * V;
#pragma unroll
    for (int v = 0; v < V; v++) acc[v] = hr[v] * dn;   // self-loop (x dn again at end)

    const int beg = rowptr[node];
    const int end = rowptr[node + 1];
    for (int j = beg; j < end; ++j) {
        int s = srcids[j];
        float w = dinv[s];
        const float* hs = h + (size_t)s * F + lane * V;
#pragma unroll
        for (int v = 0; v < V; v++) acc[v] += hs[v] * w;
    }

    float* op = out + (size_t)node * F + lane * V;
#pragma unroll
    for (int v = 0; v < V; v++) {
        float r = acc[v] * dn + bias[lane * V + v];
        if (RELU) r = fmaxf(r, 0.f);
        op[v] = r;
    }
}

// ---------------- final: out = log_softmax(h2 @ Wo + bo) ----------------
__launch_bounds__(256)
__global__ void out_kernel(const float* __restrict__ h2, const float* __restrict__ Wo,
                           const float* __restrict__ bo, float* __restrict__ out, int n) {
    __shared__ float Ws[64 * 40];
    __shared__ float bs[40];
    for (int i = threadIdx.x; i < 64 * 40; i += 256) Ws[i] = Wo[i];
    if (threadIdx.x < 40) bs[threadIdx.x] = bo[threadIdx.x];
    __syncthreads();

    int row = blockIdx.x * 256 + threadIdx.x;
    if (row >= n) return;

    float acc[40];
#pragma unroll
    for (int j = 0; j < 40; j++) acc[j] = 0.f;

    const float* hr = h2 + (size_t)row * 64;
#pragma unroll 4
    for (int k = 0; k < 64; k++) {
        float a = hr[k];
#pragma unroll
        for (int j = 0; j < 40; j++) acc[j] += a * Ws[k * 40 + j];
    }

    float m = -1e30f;
#pragma unroll
    for (int j = 0; j < 40; j++) {
        acc[j] += bs[j];
        m = fmaxf(m, acc[j]);
    }
    float s = 0.f;
#pragma unroll
    for (int j = 0; j < 40; j++) s += expf(acc[j] - m);
    float lse = m + logf(s);

    float* op = out + (size_t)row * 40;
#pragma unroll
    for (int j = 0; j < 40; j++) op[j] = acc[j] - lse;
}

extern "C" void kernel_launch(void* const* d_in, const int* in_sizes, int n_in,
                              void* d_out, int out_size, void* d_ws, size_t ws_size,
                              hipStream_t stream) {
    const float* x  = (const float*)d_in[0];
    const int*   ei = (const int*)d_in[1];
    const float* W1 = (const float*)d_in[2];
    const float* b1 = (const float*)d_in[3];
    const float* W2 = (const float*)d_in[4];
    const float* b2 = (const float*)d_in[5];
    const float* Wo = (const float*)d_in[6];
    const float* bo = (const float*)d_in[7];
    float* out = (float*)d_out;

    const int HID = in_sizes[3];            // 128
    const int IN  = in_sizes[2] / HID;      // 256
    const int HID1 = in_sizes[5];           // 64
    const int N = in_sizes[0] / IN;         // 100000
    const int E = in_sizes[1] / 2;          // 1600000
    const int* src = ei;
    const int* dst = ei + E;

    char* ws = (char*)d_ws;
    size_t off = 0;
    auto alloc = [&](size_t bytes) -> void* {
        void* p = ws + off;
        off += (bytes + 255) / 256 * 256;
        return p;
    };
    float* dinv   = (float*)alloc((size_t)N * 4);
    int*   rowptr = (int*)alloc((size_t)(N + 1) * 4);
    int*   cnt    = (int*)alloc((size_t)N * 4);
    int*   fillc  = (int*)alloc((size_t)N * 4);
    int*   bsum   = (int*)alloc(4096);
    int*   srcids = (int*)alloc((size_t)E * 4);
    float* bufA   = (float*)alloc((size_t)N * 128 * 4);
    float* bufB   = (float*)alloc((size_t)N * 128 * 4);

    // degree + norm
    hipMemsetAsync(cnt, 0, (size_t)N * 4, stream);
    count_kernel<<<(E + 255) / 256, 256, 0, stream>>>(dst, E, cnt);
    dinv_kernel<<<(N + 255) / 256, 256, 0, stream>>>(cnt, dinv, N);

    // CSR
    int nb = (N + 255) / 256;
    scan_block<<<nb, 256, 0, stream>>>(cnt, rowptr, bsum, N);
    scan_sums<<<1, 512, 0, stream>>>(bsum, rowptr, nb, N);
    scan_add<<<nb, 256, 0, stream>>>(rowptr, bsum, N);
    hipMemsetAsync(fillc, 0, (size_t)N * 4, stream);
    fill_kernel<<<(E + 255) / 256, 256, 0, stream>>>(src, dst, E, rowptr, fillc, srcids);

    // layer 1: h_lin1 = x @ W1 ; h1 = relu(agg(h_lin1) + b1)
    gemm_nn<64, 128, 32, 4, 8><<<dim3(1, (N + 63) / 64), 256, 0, stream>>>(x, W1, bufA, N, 128, IN);
    agg_kernel<128, true><<<(N + 3) / 4, 256, 0, stream>>>(bufA, b1, rowptr, srcids, dinv, bufB, N);

    // layer 2: h_lin2 = h1 @ W2 ; h2 = agg(h_lin2) + b2
    gemm_nn<64, 64, 32, 4, 4><<<dim3(1, (N + 63) / 64), 256, 0, stream>>>(bufB, W2, bufA, N, 64, HID);
    agg_kernel<64, false><<<(N + 3) / 4, 256, 0, stream>>>(bufA, b2, rowptr, srcids, dinv, bufB, N);

    // output head + log_softmax
    out_kernel<<<(N + 255) / 256, 256, 0, stream>>>(bufB, Wo, bo, out, N);
    (void)ws_size; (void)n_in; (void)out_size; (void)HID1;
}

// Round 2
// 392.043 us; speedup vs baseline: 1.6495x; 1.6495x over previous
//
#include <hip/hip_runtime.h>
#include <hip/hip_bf16.h>

typedef unsigned short u16;
typedef unsigned int u32;
typedef __attribute__((ext_vector_type(8))) short bf16x8;   // 8 bf16 (4 VGPRs)
typedef __attribute__((ext_vector_type(4))) float f32x4;
typedef __attribute__((ext_vector_type(4))) u16 u16x4;

__device__ __forceinline__ u16 f2bf(float f) {
    union { float f; u32 u; } v; v.f = f;
    u32 r = v.u + 0x7FFF + ((v.u >> 16) & 1);   // RNE
    return (u16)(r >> 16);
}
__device__ __forceinline__ float bf_lo(u32 u) {
    union { u32 u; float f; } v; v.u = u << 16; return v.f;
}
__device__ __forceinline__ float bf_hi(u32 u) {
    union { u32 u; float f; } v; v.u = u & 0xFFFF0000u; return v.f;
}

// ---------------- degree / norm ----------------
__global__ void count_kernel(const int* __restrict__ dst, int E, int* __restrict__ cnt) {
    int e = blockIdx.x * blockDim.x + threadIdx.x;
    if (e < E) atomicAdd(&cnt[dst[e]], 1);
}

__global__ void dinv_kernel(const int* __restrict__ cnt, float* __restrict__ dinv, int n) {
    int i = blockIdx.x * blockDim.x + threadIdx.x;
    if (i < n) dinv[i] = rsqrtf((float)cnt[i] + 1.0f);
}

// ---------------- exclusive scan (3 kernels) ----------------
__global__ void scan_block(const int* __restrict__ cnt, int* __restrict__ rowptr,
                           int* __restrict__ bsum, int n) {
    __shared__ int sd[256];
    int i = blockIdx.x * 256 + threadIdx.x;
    int v = (i < n) ? cnt[i] : 0;
    sd[threadIdx.x] = v;
    __syncthreads();
    for (int off = 1; off < 256; off <<= 1) {
        int t = (threadIdx.x >= off) ? sd[threadIdx.x - off] : 0;
        __syncthreads();
        sd[threadIdx.x] += t;
        __syncthreads();
    }
    if (i < n) rowptr[i] = sd[threadIdx.x] - v;
    if (threadIdx.x == 255) bsum[blockIdx.x] = sd[255];
}

__global__ void scan_sums(int* __restrict__ bsum, int* __restrict__ rowptr, int nb, int n) {
    __shared__ int sd[512];
    int v = (threadIdx.x < nb) ? bsum[threadIdx.x] : 0;
    sd[threadIdx.x] = v;
    __syncthreads();
    for (int off = 1; off < 512; off <<= 1) {
        int t = (threadIdx.x >= off) ? sd[threadIdx.x - off] : 0;
        __syncthreads();
        sd[threadIdx.x] += t;
        __syncthreads();
    }
    if (threadIdx.x < nb) bsum[threadIdx.x] = sd[threadIdx.x] - v;
    if (threadIdx.x == 511) rowptr[n] = sd[511];
}

__global__ void scan_add(int* __restrict__ rowptr, const int* __restrict__ bsum, int n) {
    int i = blockIdx.x * 256 + threadIdx.x;
    if (i < n) rowptr[i] += bsum[blockIdx.x];
}

// ---------------- CSR fill ----------------
__global__ void fill_kernel(const int* __restrict__ src, const int* __restrict__ dst, int E,
                            const int* __restrict__ rowptr, int* __restrict__ fill,
                            int* __restrict__ srcids) {
    int e = blockIdx.x * blockDim.x + threadIdx.x;
    if (e < E) {
        int d = dst[e];
        int p = atomicAdd(&fill[d], 1);
        srcids[rowptr[d] + p] = src[e];
    }
}

// ---------------- weight transpose+convert: Bt[n][k] = bf16(W[k][n]) ----------------
__global__ void conv_w(const float* __restrict__ W, u16* __restrict__ Bt, int K, int N) {
    int i = blockIdx.x * 256 + threadIdx.x;
    if (i < K * N) {
        int n = i / K, k = i - n * K;
        Bt[i] = f2bf(W[(size_t)k * N + n]);
    }
}

// ---------------- MFMA bf16 GEMM: G[m][n] = bf16( (A @ Bt^T)[m][n] * dinv[m] ) ----------------
// A: [M][K] (fp32 or bf16 row-major), Bt: [BN][K] bf16, G: [M][BN] bf16
template <int K, int BN, int IFR, int JFR, int WM, int WN, bool ABF16>
__launch_bounds__(256)
__global__ void gemm_mfma(const void* __restrict__ Av, const u16* __restrict__ Bt,
                          const float* __restrict__ dinv, u16* __restrict__ G, int M) {
    constexpr int BM = 128, BK = 32;
    __shared__ u16 As[BM][BK];   // 64 B rows -> conflict-free b128 frag reads
    __shared__ u16 Bs[BN][BK];
    const int tid = threadIdx.x;
    const int lane = tid & 63, wave = tid >> 6;
    const int r = lane & 15, g = lane >> 4;
    const int wm = wave % WM, wn = wave / WM;
    const int m0 = blockIdx.x * BM;

    f32x4 acc[IFR][JFR];
#pragma unroll
    for (int i = 0; i < IFR; i++)
#pragma unroll
        for (int j = 0; j < JFR; j++) acc[i][j] = (f32x4){0.f, 0.f, 0.f, 0.f};

    for (int k0 = 0; k0 < K; k0 += BK) {
        // stage A tile (128 x 32)
#pragma unroll
        for (int p = 0; p < 4; p++) {
            int q = tid + p * 256;
            int row = q >> 3, kq = (q & 7) << 2;
            int gr = m0 + row; if (gr >= M) gr = M - 1;   // clamp; stores guarded
            if constexpr (ABF16) {
                const u16* A = (const u16*)Av;
                *(u16x4*)&As[row][kq] = *(const u16x4*)(A + (size_t)gr * K + k0 + kq);
            } else {
                const float* A = (const float*)Av;
                float4 a = *(const float4*)(A + (size_t)gr * K + k0 + kq);
                u16x4 v = { f2bf(a.x), f2bf(a.y), f2bf(a.z), f2bf(a.w) };
                *(u16x4*)&As[row][kq] = v;
            }
        }
        // stage B tile (BN x 32) from Bt[n][K]
#pragma unroll
        for (int p = 0; p < BN / 32; p++) {
            int q = tid + p * 256;
            int row = q >> 3, kq = (q & 7) << 2;
            *(u16x4*)&Bs[row][kq] = *(const u16x4*)(Bt + (size_t)row * K + k0 + kq);
        }
        __syncthreads();

        bf16x8 af[IFR], bfr[JFR];
#pragma unroll
        for (int i = 0; i < IFR; i++)
            af[i] = *(const bf16x8*)&As[wm * (IFR * 16) + i * 16 + r][g * 8];
#pragma unroll
        for (int j = 0; j < JFR; j++)
            bfr[j] = *(const bf16x8*)&Bs[wn * (JFR * 16) + j * 16 + r][g * 8];
#pragma unroll
        for (int i = 0; i < IFR; i++)
#pragma unroll
            for (int j = 0; j < JFR; j++)
                acc[i][j] = __builtin_amdgcn_mfma_f32_16x16x32_bf16(af[i], bfr[j], acc[i][j], 0, 0, 0);
        __syncthreads();
    }

    // epilogue: C/D layout col=lane&15, row=(lane>>4)*4+reg
#pragma unroll
    for (int i = 0; i < IFR; i++) {
#pragma unroll
        for (int t = 0; t < 4; t++) {
            int row = m0 + wm * (IFR * 16) + i * 16 + g * 4 + t;
            if (row < M) {
                float dn = dinv[row];
#pragma unroll
                for (int j = 0; j < JFR; j++) {
                    int col = wn * (JFR * 16) + j * 16 + r;
                    G[(size_t)row * BN + col] = f2bf(acc[i][j][t] * dn);
                }
            }
        }
    }
}

// ---------------- agg, F=128 bf16 in (pre-scaled), bf16 out (bias+relu) ----------------
__launch_bounds__(256)
__global__ void agg128(const u32* __restrict__ g1, const float* __restrict__ bias,
                       const int* __restrict__ rowptr, const int* __restrict__ srcids,
                       const float* __restrict__ dinv, u32* __restrict__ h1, int n) {
    const int wv = threadIdx.x >> 6, lane = threadIdx.x & 63;
    const int node = blockIdx.x * 4 + wv;
    if (node >= n) return;
    const float dn = dinv[node];
    u32 self = g1[(size_t)node * 64 + lane];
    float a0 = bf_lo(self), a1 = bf_hi(self);
    int j = rowptr[node];
    const int end = rowptr[node + 1];
    for (; j + 4 <= end; j += 4) {            // 4 independent row loads in flight
        int s0 = srcids[j], s1 = srcids[j + 1], s2 = srcids[j + 2], s3 = srcids[j + 3];
        u32 v0 = g1[(size_t)s0 * 64 + lane];
        u32 v1 = g1[(size_t)s1 * 64 + lane];
        u32 v2 = g1[(size_t)s2 * 64 + lane];
        u32 v3 = g1[(size_t)s3 * 64 + lane];
        a0 += (bf_lo(v0) + bf_lo(v1)) + (bf_lo(v2) + bf_lo(v3));
        a1 += (bf_hi(v0) + bf_hi(v1)) + (bf_hi(v2) + bf_hi(v3));
    }
    for (; j < end; j++) {
        u32 v = g1[(size_t)srcids[j] * 64 + lane];
        a0 += bf_lo(v); a1 += bf_hi(v);
    }
    float r0 = fmaxf(a0 * dn + bias[lane * 2], 0.f);
    float r1 = fmaxf(a1 * dn + bias[lane * 2 + 1], 0.f);
    h1[(size_t)node * 64 + lane] = (u32)f2bf(r0) | ((u32)f2bf(r1) << 16);
}

// ---------------- agg, F=64 bf16 in (pre-scaled), fp32 out; 2 edges per wave ----------------
__launch_bounds__(256)
__global__ void agg64(const u32* __restrict__ g2, const float* __restrict__ bias,
                      const int* __restrict__ rowptr, const int* __restrict__ srcids,
                      const float* __restrict__ dinv, float* __restrict__ h2, int n) {
    const int wv = threadIdx.x >> 6, lane = threadIdx.x & 63;
    const int node = blockIdx.x * 4 + wv;
    if (node >= n) return;
    const int p = lane >> 5, c = lane & 31;
    const float dn = dinv[node];
    float a0 = 0.f, a1 = 0.f;
    if (p == 0) {
        u32 self = g2[(size_t)node * 32 + c];
        a0 = bf_lo(self); a1 = bf_hi(self);
    }
    const int end = rowptr[node + 1];
    int j = rowptr[node] + p;
    for (; j + 2 < end; j += 4) {             // 2 edges per half-wave in flight
        int sa = srcids[j], sb = srcids[j + 2];
        u32 va = g2[(size_t)sa * 32 + c];
        u32 vb = g2[(size_t)sb * 32 + c];
        a0 += bf_lo(va) + bf_lo(vb);
        a1 += bf_hi(va) + bf_hi(vb);
    }
    for (; j < end; j += 2) {
        u32 v = g2[(size_t)srcids[j] * 32 + c];
        a0 += bf_lo(v); a1 += bf_hi(v);
    }
    a0 += __shfl_xor(a0, 32);
    a1 += __shfl_xor(a1, 32);
    if (p == 0) {
        float2 w;
        w.x = a0 * dn + bias[c * 2];
        w.y = a1 * dn + bias[c * 2 + 1];
        *(float2*)&h2[(size_t)node * 64 + c * 2] = w;
    }
}

// ---------------- final: out = log_softmax(h2 @ Wo + bo) ----------------
__launch_bounds__(256)
__global__ void out_kernel(const float* __restrict__ h2, const float* __restrict__ Wo,
                           const float* __restrict__ bo, float* __restrict__ out, int n) {
    __shared__ float Ws[64 * 40];
    __shared__ float bs[40];
    for (int i = threadIdx.x; i < 64 * 40; i += 256) Ws[i] = Wo[i];
    if (threadIdx.x < 40) bs[threadIdx.x] = bo[threadIdx.x];
    __syncthreads();

    int row = blockIdx.x * 256 + threadIdx.x;
    if (row >= n) return;

    float acc[40];
#pragma unroll
    for (int j = 0; j < 40; j++) acc[j] = 0.f;

    const float4* hr = (const float4*)(h2 + (size_t)row * 64);
#pragma unroll 4
    for (int k4 = 0; k4 < 16; k4++) {
        float4 h4 = hr[k4];
        float hv[4] = {h4.x, h4.y, h4.z, h4.w};
#pragma unroll
        for (int u = 0; u < 4; u++) {
            float a = hv[u];
            const float* wrow = &Ws[(k4 * 4 + u) * 40];
#pragma unroll
            for (int j = 0; j < 40; j++) acc[j] += a * wrow[j];
        }
    }

    float m = -1e30f;
#pragma unroll
    for (int j = 0; j < 40; j++) { acc[j] += bs[j]; m = fmaxf(m, acc[j]); }
    float s = 0.f;
#pragma unroll
    for (int j = 0; j < 40; j++) s += expf(acc[j] - m);
    float lse = m + logf(s);

    float* op = out + (size_t)row * 40;
#pragma unroll
    for (int j4 = 0; j4 < 10; j4++) {
        float4 w = { acc[j4 * 4] - lse, acc[j4 * 4 + 1] - lse,
                     acc[j4 * 4 + 2] - lse, acc[j4 * 4 + 3] - lse };
        *(float4*)(op + j4 * 4) = w;
    }
}

extern "C" void kernel_launch(void* const* d_in, const int* in_sizes, int n_in,
                              void* d_out, int out_size, void* d_ws, size_t ws_size,
                              hipStream_t stream) {
    const float* x  = (const float*)d_in[0];
    const int*   ei = (const int*)d_in[1];
    const float* W1 = (const float*)d_in[2];
    const float* b1 = (const float*)d_in[3];
    const float* W2 = (const float*)d_in[4];
    const float* b2 = (const float*)d_in[5];
    const float* Wo = (const float*)d_in[6];
    const float* bo = (const float*)d_in[7];
    float* out = (float*)d_out;

    const int HID  = in_sizes[3];           // 128
    const int IN   = in_sizes[2] / HID;     // 256
    const int HID1 = in_sizes[5];           // 64
    const int N = in_sizes[0] / IN;         // 100000
    const int E = in_sizes[1] / 2;          // 1600000
    const int* src = ei;
    const int* dst = ei + E;

    char* ws = (char*)d_ws;
    size_t off = 0;
    auto alloc = [&](size_t bytes) -> void* {
        void* p = ws + off;
        off += (bytes + 255) / 256 * 256;
        return p;
    };
    float* dinv   = (float*)alloc((size_t)N * 4);
    int*   rowptr = (int*)alloc((size_t)(N + 1) * 4);
    int*   cnt    = (int*)alloc((size_t)N * 4);
    int*   fillc  = (int*)alloc((size_t)N * 4);
    int*   bsum   = (int*)alloc(4096);
    int*   srcids = (int*)alloc((size_t)E * 4);
    u16*   W1t    = (u16*)alloc((size_t)IN * HID * 2);     // [128][256] bf16
    u16*   W2t    = (u16*)alloc((size_t)HID * HID1 * 2);   // [64][128] bf16
    u16*   g1     = (u16*)alloc((size_t)N * HID * 2);      // bf16 [N][128]
    u16*   h1     = (u16*)alloc((size_t)N * HID * 2);      // bf16 [N][128]
    u16*   g2     = (u16*)alloc((size_t)N * HID1 * 2);     // bf16 [N][64]
    float* h2     = (float*)alloc((size_t)N * HID1 * 4);   // fp32 [N][64]

    // degree + norm
    hipMemsetAsync(cnt, 0, (size_t)N * 4, stream);
    count_kernel<<<(E + 255) / 256, 256, 0, stream>>>(dst, E, cnt);
    dinv_kernel<<<(N + 255) / 256, 256, 0, stream>>>(cnt, dinv, N);

    // CSR
    int nb = (N + 255) / 256;
    scan_block<<<nb, 256, 0, stream>>>(cnt, rowptr, bsum, N);
    scan_sums<<<1, 512, 0, stream>>>(bsum, rowptr, nb, N);
    scan_add<<<nb, 256, 0, stream>>>(rowptr, bsum, N);
    hipMemsetAsync(fillc, 0, (size_t)N * 4, stream);
    fill_kernel<<<(E + 255) / 256, 256, 0, stream>>>(src, dst, E, rowptr, fillc, srcids);

    // weights -> bf16 transposed
    conv_w<<<(IN * HID + 255) / 256, 256, 0, stream>>>(W1, W1t, IN, HID);
    conv_w<<<(HID * HID1 + 255) / 256, 256, 0, stream>>>(W2, W2t, HID, HID1);

    const int gblocks = (N + 127) / 128;
    // layer 1: g1 = bf16((x @ W1) * dinv); h1 = bf16(relu(agg(g1)*dinv + b1))
    gemm_mfma<256, 128, 4, 4, 2, 2, false><<<gblocks, 256, 0, stream>>>(x, W1t, dinv, g1, N);
    agg128<<<(N + 3) / 4, 256, 0, stream>>>((const u32*)g1, b1, rowptr, srcids, dinv, (u32*)h1, N);

    // layer 2: g2 = bf16((h1 @ W2) * dinv); h2 = agg(g2)*dinv + b2  (fp32)
    gemm_mfma<128, 64, 2, 4, 4, 1, true><<<gblocks, 256, 0, stream>>>(h1, W2t, dinv, g2, N);
    agg64<<<(N + 3) / 4, 256, 0, stream>>>((const u32*)g2, b2, rowptr, srcids, dinv, h2, N);

    // output head + log_softmax
    out_kernel<<<(N + 255) / 256, 256, 0, stream>>>(h2, Wo, bo, out, N);
    (void)ws_size; (void)n_in; (void)out_size;
}

// Round 3
// 381.783 us; speedup vs baseline: 1.6938x; 1.0269x over previous
//
#include <hip/hip_runtime.h>
#include <hip/hip_bf16.h>

typedef unsigned short u16;
typedef unsigned int u32;
typedef __attribute__((ext_vector_type(8))) short bf16x8;   // 8 bf16 (4 VGPRs)
typedef __attribute__((ext_vector_type(4))) float f32x4;
typedef __attribute__((ext_vector_type(4))) u16 u16x4;

__device__ __forceinline__ u16 f2bf(float f) {
    union { float f; u32 u; } v; v.f = f;
    u32 r = v.u + 0x7FFF + ((v.u >> 16) & 1);   // RNE
    return (u16)(r >> 16);
}
__device__ __forceinline__ float bf_lo(u32 u) {
    union { u32 u; float f; } v; v.u = u << 16; return v.f;
}
__device__ __forceinline__ float bf_hi(u32 u) {
    union { u32 u; float f; } v; v.u = u & 0xFFFF0000u; return v.f;
}

// ---------------- degree ----------------
__global__ void count_kernel(const int* __restrict__ dst, int E, int* __restrict__ cnt) {
    int e = blockIdx.x * blockDim.x + threadIdx.x;
    if (e < E) atomicAdd(&cnt[dst[e]], 1);
}

// ---------------- exclusive scan (3 kernels); scan_block also emits dinv ----------------
__global__ void scan_block(const int* __restrict__ cnt, int* __restrict__ rowptr,
                           int* __restrict__ bsum, float* __restrict__ dinv, int n) {
    __shared__ int sd[256];
    int i = blockIdx.x * 256 + threadIdx.x;
    int v = (i < n) ? cnt[i] : 0;
    if (i < n) dinv[i] = rsqrtf((float)v + 1.0f);
    sd[threadIdx.x] = v;
    __syncthreads();
    for (int off = 1; off < 256; off <<= 1) {
        int t = (threadIdx.x >= off) ? sd[threadIdx.x - off] : 0;
        __syncthreads();
        sd[threadIdx.x] += t;
        __syncthreads();
    }
    if (i < n) rowptr[i] = sd[threadIdx.x] - v;
    if (threadIdx.x == 255) bsum[blockIdx.x] = sd[255];
}

__global__ void scan_sums(int* __restrict__ bsum, int* __restrict__ rowptr, int nb, int n) {
    __shared__ int sd[512];
    int v = (threadIdx.x < nb) ? bsum[threadIdx.x] : 0;
    sd[threadIdx.x] = v;
    __syncthreads();
    for (int off = 1; off < 512; off <<= 1) {
        int t = (threadIdx.x >= off) ? sd[threadIdx.x - off] : 0;
        __syncthreads();
        sd[threadIdx.x] += t;
        __syncthreads();
    }
    if (threadIdx.x < nb) bsum[threadIdx.x] = sd[threadIdx.x] - v;
    if (threadIdx.x == 511) rowptr[n] = sd[511];
}

__global__ void scan_add(int* __restrict__ rowptr, const int* __restrict__ bsum,
                         int* __restrict__ fillc, int n) {
    int i = blockIdx.x * 256 + threadIdx.x;
    if (i < n) {
        rowptr[i] += bsum[blockIdx.x];
        fillc[i] = 0;
    }
}

// ---------------- CSR fill, dst-range pass (L2-resident scatter window) ----------------
__global__ void fill_pass(const int* __restrict__ src, const int* __restrict__ dst, int E,
                          const int* __restrict__ rowptr, int* __restrict__ fill,
                          int* __restrict__ srcids, int lo, int hi) {
    int e = blockIdx.x * blockDim.x + threadIdx.x;
    if (e < E) {
        int d = dst[e];
        if (d >= lo && d < hi) {
            int p = atomicAdd(&fill[d], 1);
            srcids[rowptr[d] + p] = src[e];
        }
    }
}

// ---------------- weight transpose+convert (both layers in one kernel) ----------------
// Bt[n][k] = bf16(W[k][n])
__global__ void conv_w2(const float* __restrict__ W1, u16* __restrict__ B1, int K1, int N1,
                        const float* __restrict__ W2, u16* __restrict__ B2, int K2, int N2) {
    int i = blockIdx.x * 256 + threadIdx.x;
    int sz1 = K1 * N1;
    if (i < sz1) {
        int n = i / K1, k = i - n * K1;
        B1[i] = f2bf(W1[(size_t)k * N1 + n]);
    } else if (i - sz1 < K2 * N2) {
        int j = i - sz1;
        int n = j / K2, k = j - n * K2;
        B2[j] = f2bf(W2[(size_t)k * N2 + n]);
    }
}

// ---------------- MFMA bf16 GEMM: G[m][n] = bf16( (A @ Bt^T)[m][n] * dinv[m] ) ----------------
template <int K, int BN, int IFR, int JFR, int WM, int WN, bool ABF16>
__launch_bounds__(256)
__global__ void gemm_mfma(const void* __restrict__ Av, const u16* __restrict__ Bt,
                          const float* __restrict__ dinv, u16* __restrict__ G, int M) {
    constexpr int BM = 128, BK = 32;
    __shared__ u16 As[BM][BK];   // 64 B rows -> conflict-free b128 frag reads
    __shared__ u16 Bs[BN][BK];
    const int tid = threadIdx.x;
    const int lane = tid & 63, wave = tid >> 6;
    const int r = lane & 15, g = lane >> 4;
    const int wm = wave % WM, wn = wave / WM;
    const int m0 = blockIdx.x * BM;

    f32x4 acc[IFR][JFR];
#pragma unroll
    for (int i = 0; i < IFR; i++)
#pragma unroll
        for (int j = 0; j < JFR; j++) acc[i][j] = (f32x4){0.f, 0.f, 0.f, 0.f};

    for (int k0 = 0; k0 < K; k0 += BK) {
#pragma unroll
        for (int p = 0; p < 4; p++) {
            int q = tid + p * 256;
            int row = q >> 3, kq = (q & 7) << 2;
            int gr = m0 + row; if (gr >= M) gr = M - 1;   // clamp; stores guarded
            if constexpr (ABF16) {
                const u16* A = (const u16*)Av;
                *(u16x4*)&As[row][kq] = *(const u16x4*)(A + (size_t)gr * K + k0 + kq);
            } else {
                const float* A = (const float*)Av;
                float4 a = *(const float4*)(A + (size_t)gr * K + k0 + kq);
                u16x4 v = { f2bf(a.x), f2bf(a.y), f2bf(a.z), f2bf(a.w) };
                *(u16x4*)&As[row][kq] = v;
            }
        }
#pragma unroll
        for (int p = 0; p < BN / 32; p++) {
            int q = tid + p * 256;
            int row = q >> 3, kq = (q & 7) << 2;
            *(u16x4*)&Bs[row][kq] = *(const u16x4*)(Bt + (size_t)row * K + k0 + kq);
        }
        __syncthreads();

        bf16x8 af[IFR], bfr[JFR];
#pragma unroll
        for (int i = 0; i < IFR; i++)
            af[i] = *(const bf16x8*)&As[wm * (IFR * 16) + i * 16 + r][g * 8];
#pragma unroll
        for (int j = 0; j < JFR; j++)
            bfr[j] = *(const bf16x8*)&Bs[wn * (JFR * 16) + j * 16 + r][g * 8];
#pragma unroll
        for (int i = 0; i < IFR; i++)
#pragma unroll
            for (int j = 0; j < JFR; j++)
                acc[i][j] = __builtin_amdgcn_mfma_f32_16x16x32_bf16(af[i], bfr[j], acc[i][j], 0, 0, 0);
        __syncthreads();
    }

    // C/D layout: col=lane&15, row=(lane>>4)*4+reg
#pragma unroll
    for (int i = 0; i < IFR; i++) {
#pragma unroll
        for (int t = 0; t < 4; t++) {
            int row = m0 + wm * (IFR * 16) + i * 16 + g * 4 + t;
            if (row < M) {
                float dn = dinv[row];
#pragma unroll
                for (int j = 0; j < JFR; j++) {
                    int col = wn * (JFR * 16) + j * 16 + r;
                    G[(size_t)row * BN + col] = f2bf(acc[i][j][t] * dn);
                }
            }
        }
    }
}

// ---------------- agg, F=128 bf16 in (pre-scaled), bf16 out (bias+relu) ----------------
__launch_bounds__(256)
__global__ void agg128(const u32* __restrict__ g1, const float* __restrict__ bias,
                       const int* __restrict__ rowptr, const int* __restrict__ srcids,
                       const float* __restrict__ dinv, u32* __restrict__ h1, int n) {
    const int wv = threadIdx.x >> 6, lane = threadIdx.x & 63;
    const int node = blockIdx.x * 4 + wv;
    if (node >= n) return;
    const float dn = dinv[node];
    u32 self = g1[(size_t)node * 64 + lane];
    float a0 = bf_lo(self), a1 = bf_hi(self);
    int j = rowptr[node];
    const int end = rowptr[node + 1];
    for (; j + 4 <= end; j += 4) {
        int s0 = srcids[j], s1 = srcids[j + 1], s2 = srcids[j + 2], s3 = srcids[j + 3];
        u32 v0 = g1[(size_t)s0 * 64 + lane];
        u32 v1 = g1[(size_t)s1 * 64 + lane];
        u32 v2 = g1[(size_t)s2 * 64 + lane];
        u32 v3 = g1[(size_t)s3 * 64 + lane];
        a0 += (bf_lo(v0) + bf_lo(v1)) + (bf_lo(v2) + bf_lo(v3));
        a1 += (bf_hi(v0) + bf_hi(v1)) + (bf_hi(v2) + bf_hi(v3));
    }
    for (; j < end; j++) {
        u32 v = g1[(size_t)srcids[j] * 64 + lane];
        a0 += bf_lo(v); a1 += bf_hi(v);
    }
    float r0 = fmaxf(a0 * dn + bias[lane * 2], 0.f);
    float r1 = fmaxf(a1 * dn + bias[lane * 2 + 1], 0.f);
    h1[(size_t)node * 64 + lane] = (u32)f2bf(r0) | ((u32)f2bf(r1) << 16);
}

// ---------------- agg, F=64 bf16 in (pre-scaled), fp32 out; 2 edges per wave ----------------
__launch_bounds__(256)
__global__ void agg64(const u32* __restrict__ g2, const float* __restrict__ bias,
                      const int* __restrict__ rowptr, const int* __restrict__ srcids,
                      const float* __restrict__ dinv, float* __restrict__ h2, int n) {
    const int wv = threadIdx.x >> 6, lane = threadIdx.x & 63;
    const int node = blockIdx.x * 4 + wv;
    if (node >= n) return;
    const int p = lane >> 5, c = lane & 31;
    const float dn = dinv[node];
    float a0 = 0.f, a1 = 0.f;
    if (p == 0) {
        u32 self = g2[(size_t)node * 32 + c];
        a0 = bf_lo(self); a1 = bf_hi(self);
    }
    const int end = rowptr[node + 1];
    int j = rowptr[node] + p;
    for (; j + 2 < end; j += 4) {
        int sa = srcids[j], sb = srcids[j + 2];
        u32 va = g2[(size_t)sa * 32 + c];
        u32 vb = g2[(size_t)sb * 32 + c];
        a0 += bf_lo(va) + bf_lo(vb);
        a1 += bf_hi(va) + bf_hi(vb);
    }
    for (; j < end; j += 2) {
        u32 v = g2[(size_t)srcids[j] * 32 + c];
        a0 += bf_lo(v); a1 += bf_hi(v);
    }
    a0 += __shfl_xor(a0, 32);
    a1 += __shfl_xor(a1, 32);
    if (p == 0) {
        float2 w;
        w.x = a0 * dn + bias[c * 2];
        w.y = a1 * dn + bias[c * 2 + 1];
        *(float2*)&h2[(size_t)node * 64 + c * 2] = w;
    }
}

// ---------------- final: out = log_softmax(h2 @ Wo + bo) ----------------
__launch_bounds__(256)
__global__ void out_kernel(const float* __restrict__ h2, const float* __restrict__ Wo,
                           const float* __restrict__ bo, float* __restrict__ out, int n) {
    __shared__ float Ws[64 * 40];
    __shared__ float bs[40];
    for (int i = threadIdx.x; i < 64 * 40; i += 256) Ws[i] = Wo[i];
    if (threadIdx.x < 40) bs[threadIdx.x] = bo[threadIdx.x];
    __syncthreads();

    int row = blockIdx.x * 256 + threadIdx.x;
    if (row >= n) return;

    float acc[40];
#pragma unroll
    for (int j = 0; j < 40; j++) acc[j] = 0.f;

    const float4* hr = (const float4*)(h2 + (size_t)row * 64);
#pragma unroll 4
    for (int k4 = 0; k4 < 16; k4++) {
        float4 h4 = hr[k4];
        float hv[4] = {h4.x, h4.y, h4.z, h4.w};
#pragma unroll
        for (int u = 0; u < 4; u++) {
            float a = hv[u];
            const float* wrow = &Ws[(k4 * 4 + u) * 40];
#pragma unroll
            for (int j = 0; j < 40; j++) acc[j] += a * wrow[j];
        }
    }

    float m = -1e30f;
#pragma unroll
    for (int j = 0; j < 40; j++) { acc[j] += bs[j]; m = fmaxf(m, acc[j]); }
    float s = 0.f;
#pragma unroll
    for (int j = 0; j < 40; j++) s += expf(acc[j] - m);
    float lse = m + logf(s);

    float* op = out + (size_t)row * 40;
#pragma unroll
    for (int j4 = 0; j4 < 10; j4++) {
        float4 w = { acc[j4 * 4] - lse, acc[j4 * 4 + 1] - lse,
                     acc[j4 * 4 + 2] - lse, acc[j4 * 4 + 3] - lse };
        *(float4*)(op + j4 * 4) = w;
    }
}

extern "C" void kernel_launch(void* const* d_in, const int* in_sizes, int n_in,
                              void* d_out, int out_size, void* d_ws, size_t ws_size,
                              hipStream_t stream) {
    const float* x  = (const float*)d_in[0];
    const int*   ei = (const int*)d_in[1];
    const float* W1 = (const float*)d_in[2];
    const float* b1 = (const float*)d_in[3];
    const float* W2 = (const float*)d_in[4];
    const float* b2 = (const float*)d_in[5];
    const float* Wo = (const float*)d_in[6];
    const float* bo = (const float*)d_in[7];
    float* out = (float*)d_out;

    const int HID  = in_sizes[3];           // 128
    const int IN   = in_sizes[2] / HID;     // 256
    const int HID1 = in_sizes[5];           // 64
    const int N = in_sizes[0] / IN;         // 100000
    const int E = in_sizes[1] / 2;          // 1600000
    const int* src = ei;
    const int* dst = ei + E;

    char* ws = (char*)d_ws;
    size_t off = 0;
    auto alloc = [&](size_t bytes) -> void* {
        void* p = ws + off;
        off += (bytes + 255) / 256 * 256;
        return p;
    };
    float* dinv   = (float*)alloc((size_t)N * 4);
    int*   rowptr = (int*)alloc((size_t)(N + 1) * 4);
    int*   cnt    = (int*)alloc((size_t)N * 4);
    int*   fillc  = (int*)alloc((size_t)N * 4);
    int*   bsum   = (int*)alloc(4096);
    int*   srcids = (int*)alloc((size_t)E * 4);
    u16*   W1t    = (u16*)alloc((size_t)IN * HID * 2);     // [128][256] bf16
    u16*   W2t    = (u16*)alloc((size_t)HID * HID1 * 2);   // [64][128] bf16
    u16*   g1     = (u16*)alloc((size_t)N * HID * 2);      // bf16 [N][128]
    u16*   h1     = (u16*)alloc((size_t)N * HID * 2);      // bf16 [N][128]
    u16*   g2     = (u16*)alloc((size_t)N * HID1 * 2);     // bf16 [N][64]
    float* h2     = (float*)alloc((size_t)N * HID1 * 4);   // fp32 [N][64]

    // degree
    hipMemsetAsync(cnt, 0, (size_t)N * 4, stream);
    count_kernel<<<(E + 255) / 256, 256, 0, stream>>>(dst, E, cnt);

    // CSR (scan_block also emits dinv; scan_add also zeroes fillc)
    int nb = (N + 255) / 256;
    scan_block<<<nb, 256, 0, stream>>>(cnt, rowptr, bsum, dinv, N);
    scan_sums<<<1, 512, 0, stream>>>(bsum, rowptr, nb, N);
    scan_add<<<nb, 256, 0, stream>>>(rowptr, bsum, fillc, N);

    // CSR fill: 4 dst-range passes so the scatter window stays L2-resident
    const int NPASS = 4;
    const int R = (N + NPASS - 1) / NPASS;
    for (int p = 0; p < NPASS; p++) {
        int lo = p * R;
        int hi = (lo + R < N) ? lo + R : N;
        fill_pass<<<(E + 255) / 256, 256, 0, stream>>>(src, dst, E, rowptr, fillc, srcids, lo, hi);
    }

    // weights -> bf16 transposed (both in one launch)
    conv_w2<<<(IN * HID + HID * HID1 + 255) / 256, 256, 0, stream>>>(
        W1, W1t, IN, HID, W2, W2t, HID, HID1);

    const int gblocks = (N + 127) / 128;
    // layer 1: g1 = bf16((x @ W1) * dinv); h1 = bf16(relu(agg(g1)*dinv + b1))
    gemm_mfma<256, 128, 4, 4, 2, 2, false><<<gblocks, 256, 0, stream>>>(x, W1t, dinv, g1, N);
    agg128<<<(N + 3) / 4, 256, 0, stream>>>((const u32*)g1, b1, rowptr, srcids, dinv, (u32*)h1, N);

    // layer 2: g2 = bf16((h1 @ W2) * dinv); h2 = agg(g2)*dinv + b2  (fp32)
    gemm_mfma<128, 64, 2, 4, 4, 1, true><<<gblocks, 256, 0, stream>>>(h1, W2t, dinv, g2, N);
    agg64<<<(N + 3) / 4, 256, 0, stream>>>((const u32*)g2, b2, rowptr, srcids, dinv, h2, N);

    // output head + log_softmax
    out_kernel<<<(N + 255) / 256, 256, 0, stream>>>(h2, Wo, bo, out, N);
    (void)ws_size; (void)n_in; (void)out_size; (void)HID1;
}